// Round 1
// 223.005 us; speedup vs baseline: 1.0024x; 1.0024x over previous
//
#include <hip/hip_runtime.h>

// 3D spatial transformer (trilinear warp), voxelmorph semantics.
// vol: [B=2, X=160, Y=192, Z=160, C=1] fp32
// trf: [B=2, X=160, Y=192, Z=160, 3]  fp32 (dense displacement)
// out: same shape as vol, fp32.
//
// R5: (a) staging window clamped into the volume -> ALL blocks use the fast
// async global_load_lds path (the old scalar-clamped slow path served 40% of
// blocks; exactly-border-clamped samples now use the per-sample global
// fallback). (b) z-row XOR bank swizzle (slot z = z ^ ((y&7)<<2)): kills the
// 16-way LDS bank conflict from the y-stride (LZT=32 == bank count). LDS
// writes stay linear (global_load_lds constraint); the global SOURCE address
// is inverse-swizzled instead (involution).

#define NXD 160
#define NYD 192
#define NZD 160
#define NVOX (NXD * NYD * NZD)
#define NBATCH 2

#define TXT 8
#define TYT 16
#define TZT 16
#define LXT 16            // staged x extent
#define LYT 24            // staged y extent
#define LZT 32            // staged z extent
#define LDS_N (LXT * LYT * LZT)   // 12288 floats = 48 KB

#define TILES_X (NXD / TXT)   // 20
#define TILES_Y (NYD / TYT)   // 12
#define TILES_Z (NZD / TZT)   // 10
#define NBLOCKS (NBATCH * TILES_X * TILES_Y * TILES_Z)   // 4800

typedef float f4 __attribute__((ext_vector_type(4)));

__global__ __launch_bounds__(512)
void warp3d_kernel(const float* __restrict__ vol,
                   const float* __restrict__ trf,
                   float* __restrict__ out) {
    __shared__ float tile[LDS_N];

    int bid = blockIdx.x;
    int tz = bid % TILES_Z;
    int r  = bid / TILES_Z;
    int ty = r % TILES_Y;
    int r2 = r / TILES_Y;
    int tx = r2 % TILES_X;
    int b  = r2 / TILES_X;

    int x0t = tx * TXT, y0t = ty * TYT, z0t = tz * TZT;
    // clamped staging origin: window always fully inside the volume
    int lox = min(max(x0t - 4, 0), NXD - LXT);
    int loy = min(max(y0t - 4, 0), NYD - LYT);
    int loz = min(max(z0t - 8, 0), NZD - LZT);

    const float* vb = vol + (size_t)b * NVOX;

    int t = threadIdx.x;
    // compute-phase voxel quad: 4 z-consecutive voxels per thread
    int zq = t & 3;             // 4 z-quads (TZT/4)
    int yq = (t >> 2) & 15;     // 16 y
    int xq = t >> 6;            // 8 x (== wave id)
    int x = x0t + xq, y = y0t + yq, zb0 = z0t + zq * 4;
    size_t vox_i = (((size_t)b * NXD + x) * NYD + y) * NZD + zb0;

    // prefetch trf (12 floats = 3 aligned float4) — overlaps staging latency
    const f4* trfv = (const f4*)(trf + vox_i * 3);
    f4 t0 = trfv[0], t1 = trfv[1], t2 = trfv[2];

    // ---- stage vol tile into LDS (48 chunks x 256 floats, async 16B) ----
    {
        const float* gbase = vb + ((size_t)(lox * NYD + loy) * NZD + loz);
        int w = t >> 6;                  // wave id 0..7
        int l = t & 63;                  // lane
        int zgrp = (l & 7) << 2;         // slot z-group base within the 32-row
        int lrow = l >> 3;               // 0..7: y-row index within chunk
#pragma unroll
        for (int it = 0; it < 6; ++it) {
            int chunk = it * 8 + w;          // 0..47, wave-uniform
            int rest = chunk * 8 + lrow;     // linear (x,y) row index
            int yi = rest % LYT;
            int xi = rest / LYT;
            // inverse swizzle on the SOURCE z (XOR is an involution)
            int sz = zgrp ^ ((yi & 7) << 2);
            const float* g = gbase + (size_t)xi * (NYD * NZD) + yi * NZD + sz;
            __builtin_amdgcn_global_load_lds(
                (const __attribute__((address_space(1))) void*)g,
                (__attribute__((address_space(3))) void*)&tile[chunk * 256],
                16, 0, 0);
        }
    }
    __syncthreads();

    // ---- gather + trilinear blend, 4 voxels ----
    float dxa[4] = {t0.x, t0.w, t1.z, t2.y};
    float dya[4] = {t0.y, t1.x, t1.w, t2.z};
    float dza[4] = {t0.z, t1.y, t2.x, t2.w};

    float res[4];
#pragma unroll
    for (int j = 0; j < 4; ++j) {
        float lx = fminf(fmaxf((float)x + dxa[j], 0.0f), (float)(NXD - 1));
        float ly = fminf(fmaxf((float)y + dya[j], 0.0f), (float)(NYD - 1));
        float lz = fminf(fmaxf((float)(zb0 + j) + dza[j], 0.0f), (float)(NZD - 1));
        float fx = floorf(lx), fy = floorf(ly), fz = floorf(lz);
        int x0 = (int)fx, y0 = (int)fy, z0 = (int)fz;
        // lower-corner weights d1 = loc1 - loc (0 at clamped top border)
        float wx0 = fminf(fx + 1.0f, (float)(NXD - 1)) - lx;
        float wy0 = fminf(fy + 1.0f, (float)(NYD - 1)) - ly;
        float wz0 = fminf(fz + 1.0f, (float)(NZD - 1)) - lz;

        int ix = x0 - lox, iy = y0 - loy, iz = z0 - loz;
        bool ok = ((unsigned)ix <= LXT - 2) & ((unsigned)iy <= LYT - 2) &
                  ((unsigned)iz <= LZT - 2);
        int sx = ok ? ix : 0;            // safe LDS coords when !ok
        int sy = ok ? iy : 0;
        int sv = ok ? iz : 0;

        int r00 = (sx * LYT + sy) * LZT;     // row (x0, y0)
        int r01 = r00 + LZT;                 // row (x0, y1)
        int r10 = r00 + LYT * LZT;           // row (x1, y0)
        int r11 = r10 + LZT;                 // row (x1, y1)
        int sw0 = (sy & 7) << 2;
        int sw1 = ((sy + 1) & 7) << 2;
        int za = sv ^ sw0, zb = (sv + 1) ^ sw0;   // z, z+1 under y0-swizzle
        int zc = sv ^ sw1, zd = (sv + 1) ^ sw1;   // z, z+1 under y1-swizzle

        float v000 = tile[r00 + za], v001 = tile[r00 + zb];
        float v010 = tile[r01 + zc], v011 = tile[r01 + zd];
        float v100 = tile[r10 + za], v101 = tile[r10 + zb];
        float v110 = tile[r11 + zc], v111 = tile[r11 + zd];

        if (!ok) {   // rare: sample outside staged window -> global gather
            int x1 = min(x0 + 1, NXD - 1);
            int y1 = min(y0 + 1, NYD - 1);
            int z1 = min(z0 + 1, NZD - 1);
            size_t o00 = (size_t)(x0 * NYD + y0) * NZD;
            size_t o01 = (size_t)(x0 * NYD + y1) * NZD;
            size_t o10 = (size_t)(x1 * NYD + y0) * NZD;
            size_t o11 = (size_t)(x1 * NYD + y1) * NZD;
            v000 = vb[o00 + z0]; v001 = vb[o00 + z1];
            v010 = vb[o01 + z0]; v011 = vb[o01 + z1];
            v100 = vb[o10 + z0]; v101 = vb[o10 + z1];
            v110 = vb[o11 + z0]; v111 = vb[o11 + z1];
        }

        float wx1 = 1.0f - wx0, wy1 = 1.0f - wy0, wz1 = 1.0f - wz0;
        res[j] = wx0 * (wy0 * (wz0 * v000 + wz1 * v001) +
                        wy1 * (wz0 * v010 + wz1 * v011)) +
                 wx1 * (wy0 * (wz0 * v100 + wz1 * v101) +
                        wy1 * (wz0 * v110 + wz1 * v111));
    }

    f4 o;
    o.x = res[0]; o.y = res[1]; o.z = res[2]; o.w = res[3];
    *(f4*)(out + vox_i) = o;
}

extern "C" void kernel_launch(void* const* d_in, const int* in_sizes, int n_in,
                              void* d_out, int out_size, void* d_ws, size_t ws_size,
                              hipStream_t stream) {
    const float* vol = (const float*)d_in[0];
    const float* trf = (const float*)d_in[1];
    float* out = (float*)d_out;

    warp3d_kernel<<<NBLOCKS, 512, 0, stream>>>(vol, trf, out);
}